// Round 9
// baseline (616.387 us; speedup 1.0000x reference)
//
#include <hip/hip_runtime.h>
#include <hip/hip_bf16.h>

#define F_IN 256
#define HID  128
#define SSUB 50
#define KFIN 6400   // SSUB * HID
#define NPASS 4     // feature slices for L2-resident gather
#define FSL  32     // features per slice

typedef __attribute__((ext_vector_type(4))) float f32x4;
typedef __attribute__((ext_vector_type(8))) short bf16x8;

__device__ __forceinline__ void split_bf16(float v, short& hi, short& lo) {
    __hip_bfloat16 h = __float2bfloat16(v);
    float hf = __bfloat162float(h);
    __hip_bfloat16 l = __float2bfloat16(v - hf);   // exact residual, then RNE to bf16
    hi = __builtin_bit_cast(short, h);
    lo = __builtin_bit_cast(short, l);
}

__device__ __forceinline__ float bf2f(unsigned short u) {
    return __builtin_bit_cast(float, (unsigned)u << 16);
}

// ---------------- CSR build ----------------

__global__ void k_zero_int(int* __restrict__ p, int n) {
    int i = blockIdx.x * blockDim.x + threadIdx.x;
    if (i < n) p[i] = 0;
}

__global__ void k_hist(const int* __restrict__ dst, int* __restrict__ cnt, int E) {
    int e = blockIdx.x * blockDim.x + threadIdx.x;
    if (e < E) atomicAdd(&cnt[dst[e]], 1);
}

// ---- hierarchical exclusive scan over cnt[0..N) ----
__global__ void k_scan_local(const int* __restrict__ cnt, int* __restrict__ row_ptr,
                             float* __restrict__ dinv, int* __restrict__ blk_sum, int N) {
    __shared__ int buf[256];
    int tid = threadIdx.x;
    int i = blockIdx.x * 256 + tid;
    int v = (i < N) ? cnt[i] : 0;
    buf[tid] = v;
    __syncthreads();
    for (int off = 1; off < 256; off <<= 1) {
        int t = (tid >= off) ? buf[tid - off] : 0;
        __syncthreads();
        buf[tid] += t;
        __syncthreads();
    }
    if (i < N) {
        row_ptr[i] = buf[tid] - v;
        dinv[i] = rsqrtf((float)(v + 1));   // +1 self loop
    }
    if (tid == 255) blk_sum[blockIdx.x] = buf[255];
}

__global__ void k_scan_blk(const int* __restrict__ blk_sum, int* __restrict__ blk_off, int nblk) {
    __shared__ int buf[256];
    int tid = threadIdx.x;
    int v = (tid < nblk) ? blk_sum[tid] : 0;
    buf[tid] = v;
    __syncthreads();
    for (int off = 1; off < 256; off <<= 1) {
        int t = (tid >= off) ? buf[tid - off] : 0;
        __syncthreads();
        buf[tid] += t;
        __syncthreads();
    }
    if (tid < nblk) blk_off[tid] = buf[tid] - v;
    if (tid == 255) blk_off[nblk] = buf[255];
}

__global__ void k_scan_add(int* __restrict__ row_ptr, int* __restrict__ cursor,
                           const int* __restrict__ blk_off, int N, int nblk) {
    int i = blockIdx.x * 256 + threadIdx.x;
    if (i < N) {
        int val = row_ptr[i] + blk_off[blockIdx.x];
        row_ptr[i] = val;
        cursor[i] = val;
    }
    if (i == 0) row_ptr[N] = blk_off[nblk];
}

// XCD-sliced CSR fill (blockIdx%8 -> XCD round-robin; perf heuristic only)
__global__ void k_fill_csr(const int* __restrict__ src, const int* __restrict__ dst,
                           int* __restrict__ cursor, int* __restrict__ csr_src,
                           int E, int slice_size) {
    int slice = blockIdx.x & 7;
    int e = (blockIdx.x >> 3) * 256 + threadIdx.x;
    if (e >= E) return;
    int d = dst[e];
    if (d / slice_size != slice) return;
    int pos = atomicAdd(&cursor[d], 1);
    csr_src[pos] = src[e];
}

// ---------------- W split: fp32 (K x 128) -> fragment-linear bf16 hi/lo ----------------
template<int K>
__global__ void k_wsplit(const float* __restrict__ W, short* __restrict__ Bf) {
    int t = blockIdx.x * 256 + threadIdx.x;
    if (t >= K * HID) return;
    int k = t >> 7, n = t & 127;
    short hi, lo;
    split_bf16(W[t], hi, lo);
    int kc = k >> 5, ko = k & 31;
    int quad = ko >> 3, j = ko & 7;
    int nt = n >> 4, nc = n & 15;
    int lane = (quad << 4) | nc;
    size_t idx = (((size_t)(kc * 8 + nt)) * 64 + lane) * 8 + j;
    Bf[idx] = hi;
    Bf[(size_t)K * HID + idx] = lo;
}

// ---------------- MFMA GEMM: hs(pass-sliced bf16) = (A(MxK, fp32) @ W) * dinv[row] ----------------
// output layout: hs[pass][m][fs], pass = f>>5, fs = f&31  (3.2 MB slices, L2-resident gather)
template<int K>
__global__ __launch_bounds__(128) void k_gemm_mfma(const float* __restrict__ A,
                                                   const short* __restrict__ Bf,
                                                   const float* __restrict__ dinv,
                                                   unsigned short* __restrict__ Cb, int M) {
    constexpr int LDA = K + 4;
    constexpr int KC = K / 32;
    __shared__ float As[32 * LDA];
    int tid = threadIdx.x;
    int base = blockIdx.x * 32;

    constexpr int ITERS = (32 * (K / 4)) / 128;
#pragma unroll
    for (int i = 0; i < ITERS; ++i) {
        int f4 = tid + i * 128;
        int row = f4 / (K / 4);
        int c4 = f4 % (K / 4);
        f32x4 v = {0.f, 0.f, 0.f, 0.f};
        int m = base + row;
        if (m < M) v = *(const f32x4*)(A + (size_t)m * K + c4 * 4);
        *(f32x4*)(&As[row * LDA + c4 * 4]) = v;
    }
    __syncthreads();

    int lane = tid & 63;
    int w = tid >> 6;
    int quad = lane >> 4;
    int mrow = w * 16 + (lane & 15);
    f32x4 acc[8] = {};
    const bf16x8* BfH = (const bf16x8*)Bf;
    const bf16x8* BfL = (const bf16x8*)(Bf + (size_t)K * HID);

    for (int kc = 0; kc < KC; ++kc) {
        const float* ap = &As[mrow * LDA + kc * 32 + quad * 8];
        f32x4 a0 = *(const f32x4*)ap;
        f32x4 a1 = *(const f32x4*)(ap + 4);
        bf16x8 ahi, alo;
#pragma unroll
        for (int j2 = 0; j2 < 4; ++j2) {
            short hi, lo;
            split_bf16(a0[j2], hi, lo);
            ahi[j2] = hi; alo[j2] = lo;
            split_bf16(a1[j2], hi, lo);
            ahi[4 + j2] = hi; alo[4 + j2] = lo;
        }
        bf16x8 bh[8], bl[8];
        size_t boff = ((size_t)kc * 8) * 64 + lane;
#pragma unroll
        for (int nt = 0; nt < 8; ++nt) {
            bh[nt] = BfH[boff + (size_t)nt * 64];
            bl[nt] = BfL[boff + (size_t)nt * 64];
        }
#pragma unroll
        for (int nt = 0; nt < 8; ++nt)
            acc[nt] = __builtin_amdgcn_mfma_f32_16x16x32_bf16(ahi, bh[nt], acc[nt], 0, 0, 0);
#pragma unroll
        for (int nt = 0; nt < 8; ++nt)
            acc[nt] = __builtin_amdgcn_mfma_f32_16x16x32_bf16(alo, bh[nt], acc[nt], 0, 0, 0);
#pragma unroll
        for (int nt = 0; nt < 8; ++nt)
            acc[nt] = __builtin_amdgcn_mfma_f32_16x16x32_bf16(ahi, bl[nt], acc[nt], 0, 0, 0);
    }

    // epilogue: scale row by dinv[m], quantize to bf16, write pass-sliced
    int mbase = base + w * 16 + quad * 4;
    int ncol = lane & 15;
    float dsc[4];
#pragma unroll
    for (int r = 0; r < 4; ++r)
        dsc[r] = (mbase + r < M) ? dinv[mbase + r] : 0.f;
#pragma unroll
    for (int nt = 0; nt < 8; ++nt) {
        int pass = nt >> 1;
        int fs = ((nt & 1) << 4) | ncol;
#pragma unroll
        for (int r = 0; r < 4; ++r) {
            int m = mbase + r;
            if (m < M) {
                __hip_bfloat16 b = __float2bfloat16(acc[nt][r] * dsc[r]);
                Cb[((size_t)pass * M + m) * FSL + fs] = __builtin_bit_cast(unsigned short, b);
            }
        }
    }
}

// ---------------- CSR aggregation, one feature-slice pass ----------------
// hsp = hs + pass*M*32 (3.2 MB slice, L2-resident). 4 nodes per 128-thread block.
// out[n][pass*32+f] = dinv[n] * (hsp[n][f] + sum_in hsp[src][f]) + bias  (+relu)
__global__ __launch_bounds__(128) void k_agg_pass(const unsigned short* __restrict__ hsp,
                                                  const int* __restrict__ row_ptr,
                                                  const int* __restrict__ csr_src,
                                                  const float* __restrict__ dinv,
                                                  const float* __restrict__ bias,
                                                  float* __restrict__ out,
                                                  int relu, int pass, int M) {
    int tid = threadIdx.x;
    int n = blockIdx.x * 4 + (tid >> 5);
    int f = tid & 31;
    if (n >= M) return;
    int beg = row_ptr[n];
    int end = row_ptr[n + 1];
    float acc = bf2f(hsp[(size_t)n * FSL + f]);   // self loop (pre-scaled)
    int k = beg;
    for (; k + 3 < end; k += 4) {
        int s0 = csr_src[k + 0], s1 = csr_src[k + 1];
        int s2 = csr_src[k + 2], s3 = csr_src[k + 3];
        float v0 = bf2f(hsp[(size_t)s0 * FSL + f]);
        float v1 = bf2f(hsp[(size_t)s1 * FSL + f]);
        float v2 = bf2f(hsp[(size_t)s2 * FSL + f]);
        float v3 = bf2f(hsp[(size_t)s3 * FSL + f]);
        acc += (v0 + v1) + (v2 + v3);
    }
    for (; k < end; ++k)
        acc += bf2f(hsp[(size_t)csr_src[k] * FSL + f]);
    acc = acc * dinv[n] + bias[pass * FSL + f];
    if (relu) acc = fmaxf(acc, 0.f);
    out[(size_t)n * HID + pass * FSL + f] = acc;
}

// ---------------- final linear: out = pooled @ Wl + bl (MFMA, split-K) ----------------
__global__ void k_final_init(const float* __restrict__ bl, float* __restrict__ out, int total) {
    int t = blockIdx.x * blockDim.x + threadIdx.x;
    if (t < total) out[t] = bl[t & (HID - 1)];
}

template<int KS, int TILE>
__global__ __launch_bounds__(128) void k_final_mfma(const float* __restrict__ emb,
                                                    const short* __restrict__ Bf,
                                                    float* __restrict__ out, int M) {
    constexpr int LDA = TILE + 4;
    __shared__ float As[32 * LDA];
    int tid = threadIdx.x;
    int g0 = blockIdx.x * 32;
    int k0 = blockIdx.y * KS;
    int lane = tid & 63;
    int w = tid >> 6;
    int quad = lane >> 4;
    int mrow = w * 16 + (lane & 15);
    f32x4 acc[8] = {};
    const bf16x8* BfH = (const bf16x8*)Bf;
    const bf16x8* BfL = (const bf16x8*)(Bf + (size_t)KFIN * HID);

    for (int t = 0; t < KS / TILE; ++t) {
        __syncthreads();
        constexpr int ITERS = (32 * (TILE / 4)) / 128;
#pragma unroll
        for (int i = 0; i < ITERS; ++i) {
            int f4 = tid + i * 128;
            int row = f4 / (TILE / 4);
            int c4 = f4 % (TILE / 4);
            f32x4 v = {0.f, 0.f, 0.f, 0.f};
            int m = g0 + row;
            if (m < M) v = *(const f32x4*)(emb + (size_t)m * KFIN + k0 + t * TILE + c4 * 4);
            *(f32x4*)(&As[row * LDA + c4 * 4]) = v;
        }
        __syncthreads();
        for (int kc = 0; kc < TILE / 32; ++kc) {
            int kcg = (k0 + t * TILE) / 32 + kc;
            const float* ap = &As[mrow * LDA + kc * 32 + quad * 8];
            f32x4 a0 = *(const f32x4*)ap;
            f32x4 a1 = *(const f32x4*)(ap + 4);
            bf16x8 ahi, alo;
#pragma unroll
            for (int j2 = 0; j2 < 4; ++j2) {
                short hi, lo;
                split_bf16(a0[j2], hi, lo);
                ahi[j2] = hi; alo[j2] = lo;
                split_bf16(a1[j2], hi, lo);
                ahi[4 + j2] = hi; alo[4 + j2] = lo;
            }
            bf16x8 bh[8], bl[8];
            size_t boff = (size_t)kcg * 8 * 64 + lane;
#pragma unroll
            for (int nt = 0; nt < 8; ++nt) {
                bh[nt] = BfH[boff + (size_t)nt * 64];
                bl[nt] = BfL[boff + (size_t)nt * 64];
            }
#pragma unroll
            for (int nt = 0; nt < 8; ++nt)
                acc[nt] = __builtin_amdgcn_mfma_f32_16x16x32_bf16(ahi, bh[nt], acc[nt], 0, 0, 0);
#pragma unroll
            for (int nt = 0; nt < 8; ++nt)
                acc[nt] = __builtin_amdgcn_mfma_f32_16x16x32_bf16(alo, bh[nt], acc[nt], 0, 0, 0);
#pragma unroll
            for (int nt = 0; nt < 8; ++nt)
                acc[nt] = __builtin_amdgcn_mfma_f32_16x16x32_bf16(ahi, bl[nt], acc[nt], 0, 0, 0);
        }
    }

    int mbase = g0 + w * 16 + quad * 4;
    int ncol = lane & 15;
#pragma unroll
    for (int nt = 0; nt < 8; ++nt) {
#pragma unroll
        for (int r = 0; r < 4; ++r) {
            int m = mbase + r;
            if (m < M) atomicAdd(&out[(size_t)m * HID + nt * 16 + ncol], acc[nt][r]);
        }
    }
}

extern "C" void kernel_launch(void* const* d_in, const int* in_sizes, int n_in,
                              void* d_out, int out_size, void* d_ws, size_t ws_size,
                              hipStream_t stream) {
    const float* x  = (const float*)d_in[0];
    const float* W1 = (const float*)d_in[1];
    const float* b1 = (const float*)d_in[2];
    const float* W2 = (const float*)d_in[3];
    const float* b2 = (const float*)d_in[4];
    const float* Wl = (const float*)d_in[5];
    const float* bl = (const float*)d_in[6];
    const int* edge = (const int*)d_in[7];

    const int N = in_sizes[0] / F_IN;       // 50000
    const int E = in_sizes[7] / 2;          // 1600000
    const int G = N / SSUB;                 // 1000
    const int NH = N * HID;
    const int nblk = (N + 255) / 256;       // 196
    const int slice_size = (N + 7) / 8;     // 6250

    const int* src = edge;
    const int* dst = edge + E;

    // workspace layout
    char* ws = (char*)d_ws;
    float* dinv    = (float*)ws;                 ws += (size_t)N * 4;
    int*   cnt     = (int*)ws;                   ws += (size_t)N * 4;
    int*   row_ptr = (int*)ws;                   ws += (size_t)(N + 64) * 4;
    int*   cursor  = (int*)ws;                   ws += (size_t)N * 4;
    int*   blk_sum = (int*)ws;                   ws += (size_t)(nblk + 64) * 4;
    int*   blk_off = (int*)ws;                   ws += (size_t)(nblk + 64) * 4;
    int*   csr_src = (int*)ws;                   ws += (size_t)E * 4;
    unsigned short* hs0 = (unsigned short*)ws;   ws += (size_t)NH * 2;   // bf16 gather buf L1 (pass-sliced)
    unsigned short* hs1 = (unsigned short*)ws;   ws += (size_t)NH * 2;   // bf16 gather buf L2 (pass-sliced)
    float* h       = (float*)ws;                 ws += (size_t)NH * 4;   // fp32 relu'd hidden
    short* Bf1     = (short*)ws;                 ws += (size_t)2 * F_IN * HID * 2;  // hi+lo bf16
    short* Bf2     = (short*)ws;                 ws += (size_t)2 * HID * HID * 2;
    short* Bfl     = (short*)ws;                 ws += (size_t)2 * KFIN * HID * 2;

    float* out_final = (float*)d_out;                 // G*H
    float* emb       = out_final + (size_t)G * HID;   // N*H

    // ---- CSR build (also computes dinv) ----
    k_zero_int<<<(N + 255) / 256, 256, 0, stream>>>(cnt, N);
    k_hist<<<(E + 255) / 256, 256, 0, stream>>>(dst, cnt, E);
    k_scan_local<<<nblk, 256, 0, stream>>>(cnt, row_ptr, dinv, blk_sum, N);
    k_scan_blk<<<1, 256, 0, stream>>>(blk_sum, blk_off, nblk);
    k_scan_add<<<nblk, 256, 0, stream>>>(row_ptr, cursor, blk_off, N, nblk);
    {
        int chunks = (E + 255) / 256;
        k_fill_csr<<<chunks * 8, 256, 0, stream>>>(src, dst, cursor, csr_src, E, slice_size);
    }

    // ---- weight splits ----
    k_wsplit<F_IN><<<(F_IN * HID + 255) / 256, 256, 0, stream>>>(W1, Bf1);
    k_wsplit<HID ><<<(HID  * HID + 255) / 256, 256, 0, stream>>>(W2, Bf2);
    k_wsplit<KFIN><<<(KFIN * HID + 255) / 256, 256, 0, stream>>>(Wl, Bfl);

    // ---- layer 1 ----
    k_gemm_mfma<F_IN><<<(N + 31) / 32, 128, 0, stream>>>(x, Bf1, dinv, hs0, N);
    for (int p = 0; p < NPASS; ++p)
        k_agg_pass<<<(N + 3) / 4, 128, 0, stream>>>(hs0 + (size_t)p * N * FSL,
                                                    row_ptr, csr_src, dinv, b1, h, 1, p, N);

    // ---- layer 2 ----
    k_gemm_mfma<HID><<<(N + 31) / 32, 128, 0, stream>>>(h, Bf2, dinv, hs1, N);
    for (int p = 0; p < NPASS; ++p)
        k_agg_pass<<<(N + 3) / 4, 128, 0, stream>>>(hs1 + (size_t)p * N * FSL,
                                                    row_ptr, csr_src, dinv, b2, emb, 0, p, N);

    // ---- final linear (bias init + MFMA split-K accumulate) ----
    k_final_init<<<(G * HID + 255) / 256, 256, 0, stream>>>(bl, out_final, G * HID);
    {
        dim3 grid((G + 31) / 32, 8);   // 8 K-slices of 800
        k_final_mfma<800, 160><<<grid, 128, 0, stream>>>(emb, Bfl, out_final, G);
    }
}

// Round 10
// 521.361 us; speedup vs baseline: 1.1823x; 1.1823x over previous
//
#include <hip/hip_runtime.h>
#include <hip/hip_bf16.h>

#define F_IN 256
#define HID  128
#define SSUB 50
#define KFIN 6400   // SSUB * HID

typedef __attribute__((ext_vector_type(4))) float f32x4;
typedef __attribute__((ext_vector_type(8))) short bf16x8;

__device__ __forceinline__ void split_bf16(float v, short& hi, short& lo) {
    __hip_bfloat16 h = __float2bfloat16(v);
    float hf = __bfloat162float(h);
    __hip_bfloat16 l = __float2bfloat16(v - hf);   // exact residual, then RNE to bf16
    hi = __builtin_bit_cast(short, h);
    lo = __builtin_bit_cast(short, l);
}

__device__ __forceinline__ float bf2f(unsigned short u) {
    return __builtin_bit_cast(float, (unsigned)u << 16);
}

// ---------------- CSR build ----------------

__global__ void k_hist(const int* __restrict__ dst, int* __restrict__ cnt, int E) {
    int e = blockIdx.x * blockDim.x + threadIdx.x;
    if (e < E) {
        int d = __builtin_nontemporal_load(&dst[e]);   // streaming read: don't thrash L2
        atomicAdd(&cnt[d], 1);
    }
}

// ---- hierarchical exclusive scan over cnt[0..N) ----
__global__ void k_scan_local(const int* __restrict__ cnt, int* __restrict__ row_ptr,
                             float* __restrict__ dinv, int* __restrict__ blk_sum, int N) {
    __shared__ int buf[256];
    int tid = threadIdx.x;
    int i = blockIdx.x * 256 + tid;
    int v = (i < N) ? cnt[i] : 0;
    buf[tid] = v;
    __syncthreads();
    for (int off = 1; off < 256; off <<= 1) {
        int t = (tid >= off) ? buf[tid - off] : 0;
        __syncthreads();
        buf[tid] += t;
        __syncthreads();
    }
    if (i < N) {
        row_ptr[i] = buf[tid] - v;
        dinv[i] = rsqrtf((float)(v + 1));   // +1 self loop
    }
    if (tid == 255) blk_sum[blockIdx.x] = buf[255];
}

__global__ void k_scan_blk(const int* __restrict__ blk_sum, int* __restrict__ blk_off, int nblk) {
    __shared__ int buf[256];
    int tid = threadIdx.x;
    int v = (tid < nblk) ? blk_sum[tid] : 0;
    buf[tid] = v;
    __syncthreads();
    for (int off = 1; off < 256; off <<= 1) {
        int t = (tid >= off) ? buf[tid - off] : 0;
        __syncthreads();
        buf[tid] += t;
        __syncthreads();
    }
    if (tid < nblk) blk_off[tid] = buf[tid] - v;
    if (tid == 255) blk_off[nblk] = buf[255];
}

__global__ void k_scan_add(int* __restrict__ row_ptr, int* __restrict__ cursor,
                           const int* __restrict__ blk_off, int N, int nblk) {
    int i = blockIdx.x * 256 + threadIdx.x;
    if (i < N) {
        int val = row_ptr[i] + blk_off[blockIdx.x];
        row_ptr[i] = val;
        cursor[i] = val;
    }
    if (i == 0) row_ptr[N] = blk_off[nblk];
}

// XCD-sliced CSR fill (blockIdx%8 -> XCD round-robin; perf heuristic only).
// Edge-list reads are nontemporal so the csr_src slice stays L2-resident and
// each 64B line writes back once.
__global__ void k_fill_csr(const int* __restrict__ src, const int* __restrict__ dst,
                           int* __restrict__ cursor, int* __restrict__ csr_src,
                           int E, int slice_size) {
    int slice = blockIdx.x & 7;
    int e = (blockIdx.x >> 3) * 256 + threadIdx.x;
    if (e >= E) return;
    int d = __builtin_nontemporal_load(&dst[e]);
    if (d / slice_size != slice) return;
    int pos = atomicAdd(&cursor[d], 1);
    csr_src[pos] = __builtin_nontemporal_load(&src[e]);
}

// ---------------- W split: fp32 (K x 128) -> fragment-linear bf16 hi/lo ----------------
template<int K>
__global__ void k_wsplit(const float* __restrict__ W, short* __restrict__ Bf) {
    int t = blockIdx.x * 256 + threadIdx.x;
    if (t >= K * HID) return;
    int k = t >> 7, n = t & 127;
    short hi, lo;
    split_bf16(W[t], hi, lo);
    int kc = k >> 5, ko = k & 31;
    int quad = ko >> 3, j = ko & 7;
    int nt = n >> 4, nc = n & 15;
    int lane = (quad << 4) | nc;
    size_t idx = (((size_t)(kc * 8 + nt)) * 64 + lane) * 8 + j;
    Bf[idx] = hi;
    Bf[(size_t)K * HID + idx] = lo;
}

// ---------------- MFMA GEMM: Cb(MxHID, bf16) = (A(MxK, fp32) @ W) * dinv[row] ----------------
template<int K>
__global__ __launch_bounds__(128) void k_gemm_mfma(const float* __restrict__ A,
                                                   const short* __restrict__ Bf,
                                                   const float* __restrict__ dinv,
                                                   unsigned short* __restrict__ Cb, int M) {
    constexpr int LDA = K + 4;
    constexpr int KC = K / 32;
    __shared__ float As[32 * LDA];
    int tid = threadIdx.x;
    int base = blockIdx.x * 32;

    constexpr int ITERS = (32 * (K / 4)) / 128;
#pragma unroll
    for (int i = 0; i < ITERS; ++i) {
        int f4 = tid + i * 128;
        int row = f4 / (K / 4);
        int c4 = f4 % (K / 4);
        f32x4 v = {0.f, 0.f, 0.f, 0.f};
        int m = base + row;
        if (m < M) v = *(const f32x4*)(A + (size_t)m * K + c4 * 4);
        *(f32x4*)(&As[row * LDA + c4 * 4]) = v;
    }
    __syncthreads();

    int lane = tid & 63;
    int w = tid >> 6;
    int quad = lane >> 4;
    int mrow = w * 16 + (lane & 15);
    f32x4 acc[8] = {};
    const bf16x8* BfH = (const bf16x8*)Bf;
    const bf16x8* BfL = (const bf16x8*)(Bf + (size_t)K * HID);

    for (int kc = 0; kc < KC; ++kc) {
        const float* ap = &As[mrow * LDA + kc * 32 + quad * 8];
        f32x4 a0 = *(const f32x4*)ap;
        f32x4 a1 = *(const f32x4*)(ap + 4);
        bf16x8 ahi, alo;
#pragma unroll
        for (int j2 = 0; j2 < 4; ++j2) {
            short hi, lo;
            split_bf16(a0[j2], hi, lo);
            ahi[j2] = hi; alo[j2] = lo;
            split_bf16(a1[j2], hi, lo);
            ahi[4 + j2] = hi; alo[4 + j2] = lo;
        }
        bf16x8 bh[8], bl[8];
        size_t boff = ((size_t)kc * 8) * 64 + lane;
#pragma unroll
        for (int nt = 0; nt < 8; ++nt) {
            bh[nt] = BfH[boff + (size_t)nt * 64];
            bl[nt] = BfL[boff + (size_t)nt * 64];
        }
#pragma unroll
        for (int nt = 0; nt < 8; ++nt)
            acc[nt] = __builtin_amdgcn_mfma_f32_16x16x32_bf16(ahi, bh[nt], acc[nt], 0, 0, 0);
#pragma unroll
        for (int nt = 0; nt < 8; ++nt)
            acc[nt] = __builtin_amdgcn_mfma_f32_16x16x32_bf16(alo, bh[nt], acc[nt], 0, 0, 0);
#pragma unroll
        for (int nt = 0; nt < 8; ++nt)
            acc[nt] = __builtin_amdgcn_mfma_f32_16x16x32_bf16(ahi, bl[nt], acc[nt], 0, 0, 0);
    }

    // epilogue: scale row by dinv[m], quantize to bf16 (RNE)
    int mbase = base + w * 16 + quad * 4;
    int ncol = lane & 15;
    float dsc[4];
#pragma unroll
    for (int r = 0; r < 4; ++r)
        dsc[r] = (mbase + r < M) ? dinv[mbase + r] : 0.f;
#pragma unroll
    for (int nt = 0; nt < 8; ++nt) {
#pragma unroll
        for (int r = 0; r < 4; ++r) {
            int m = mbase + r;
            if (m < M) {
                __hip_bfloat16 b = __float2bfloat16(acc[nt][r] * dsc[r]);
                Cb[(size_t)m * HID + nt * 16 + ncol] = __builtin_bit_cast(unsigned short, b);
            }
        }
    }
}

// ---------------- CSR aggregation over bf16 gather buffer ----------------
// out[n] = dinv[n] * (hs[n] + sum_in hs[src]) + bias  (+relu), fp32 accumulate/out
__global__ void k_agg(const unsigned short* __restrict__ hs, const int* __restrict__ row_ptr,
                      const int* __restrict__ csr_src, const float* __restrict__ dinv,
                      const float* __restrict__ bias, float* __restrict__ out, int relu) {
    int n = blockIdx.x;
    int j = threadIdx.x;
    int beg = row_ptr[n];
    int end = row_ptr[n + 1];
    float acc = bf2f(hs[(size_t)n * HID + j]);   // self loop (pre-scaled)
    int k = beg;
    for (; k + 3 < end; k += 4) {
        int s0 = csr_src[k + 0], s1 = csr_src[k + 1];
        int s2 = csr_src[k + 2], s3 = csr_src[k + 3];
        float v0 = bf2f(hs[(size_t)s0 * HID + j]);
        float v1 = bf2f(hs[(size_t)s1 * HID + j]);
        float v2 = bf2f(hs[(size_t)s2 * HID + j]);
        float v3 = bf2f(hs[(size_t)s3 * HID + j]);
        acc += (v0 + v1) + (v2 + v3);
    }
    for (; k < end; ++k)
        acc += bf2f(hs[(size_t)csr_src[k] * HID + j]);
    acc = acc * dinv[n] + bias[j];
    if (relu) acc = fmaxf(acc, 0.f);
    out[(size_t)n * HID + j] = acc;
}

// ---------------- final linear: out = pooled @ Wl + bl (MFMA, split-K) ----------------
__global__ void k_final_init(const float* __restrict__ bl, float* __restrict__ out, int total) {
    int t = blockIdx.x * blockDim.x + threadIdx.x;
    if (t < total) out[t] = bl[t & (HID - 1)];
}

template<int KS, int TILE>
__global__ __launch_bounds__(128) void k_final_mfma(const float* __restrict__ emb,
                                                    const short* __restrict__ Bf,
                                                    float* __restrict__ out, int M) {
    constexpr int LDA = TILE + 4;
    __shared__ float As[32 * LDA];
    int tid = threadIdx.x;
    int g0 = blockIdx.x * 32;
    int k0 = blockIdx.y * KS;
    int lane = tid & 63;
    int w = tid >> 6;
    int quad = lane >> 4;
    int mrow = w * 16 + (lane & 15);
    f32x4 acc[8] = {};
    const bf16x8* BfH = (const bf16x8*)Bf;
    const bf16x8* BfL = (const bf16x8*)(Bf + (size_t)KFIN * HID);

    for (int t = 0; t < KS / TILE; ++t) {
        __syncthreads();
        constexpr int ITERS = (32 * (TILE / 4)) / 128;
#pragma unroll
        for (int i = 0; i < ITERS; ++i) {
            int f4 = tid + i * 128;
            int row = f4 / (TILE / 4);
            int c4 = f4 % (TILE / 4);
            f32x4 v = {0.f, 0.f, 0.f, 0.f};
            int m = g0 + row;
            if (m < M) v = *(const f32x4*)(emb + (size_t)m * KFIN + k0 + t * TILE + c4 * 4);
            *(f32x4*)(&As[row * LDA + c4 * 4]) = v;
        }
        __syncthreads();
        for (int kc = 0; kc < TILE / 32; ++kc) {
            int kcg = (k0 + t * TILE) / 32 + kc;
            const float* ap = &As[mrow * LDA + kc * 32 + quad * 8];
            f32x4 a0 = *(const f32x4*)ap;
            f32x4 a1 = *(const f32x4*)(ap + 4);
            bf16x8 ahi, alo;
#pragma unroll
            for (int j2 = 0; j2 < 4; ++j2) {
                short hi, lo;
                split_bf16(a0[j2], hi, lo);
                ahi[j2] = hi; alo[j2] = lo;
                split_bf16(a1[j2], hi, lo);
                ahi[4 + j2] = hi; alo[4 + j2] = lo;
            }
            bf16x8 bh[8], bl[8];
            size_t boff = (size_t)kcg * 8 * 64 + lane;
#pragma unroll
            for (int nt = 0; nt < 8; ++nt) {
                bh[nt] = BfH[boff + (size_t)nt * 64];
                bl[nt] = BfL[boff + (size_t)nt * 64];
            }
#pragma unroll
            for (int nt = 0; nt < 8; ++nt)
                acc[nt] = __builtin_amdgcn_mfma_f32_16x16x32_bf16(ahi, bh[nt], acc[nt], 0, 0, 0);
#pragma unroll
            for (int nt = 0; nt < 8; ++nt)
                acc[nt] = __builtin_amdgcn_mfma_f32_16x16x32_bf16(alo, bh[nt], acc[nt], 0, 0, 0);
#pragma unroll
            for (int nt = 0; nt < 8; ++nt)
                acc[nt] = __builtin_amdgcn_mfma_f32_16x16x32_bf16(ahi, bl[nt], acc[nt], 0, 0, 0);
        }
    }

    int mbase = g0 + w * 16 + quad * 4;
    int ncol = lane & 15;
#pragma unroll
    for (int nt = 0; nt < 8; ++nt) {
#pragma unroll
        for (int r = 0; r < 4; ++r) {
            int m = mbase + r;
            if (m < M) atomicAdd(&out[(size_t)m * HID + nt * 16 + ncol], acc[nt][r]);
        }
    }
}

extern "C" void kernel_launch(void* const* d_in, const int* in_sizes, int n_in,
                              void* d_out, int out_size, void* d_ws, size_t ws_size,
                              hipStream_t stream) {
    const float* x  = (const float*)d_in[0];
    const float* W1 = (const float*)d_in[1];
    const float* b1 = (const float*)d_in[2];
    const float* W2 = (const float*)d_in[3];
    const float* b2 = (const float*)d_in[4];
    const float* Wl = (const float*)d_in[5];
    const float* bl = (const float*)d_in[6];
    const int* edge = (const int*)d_in[7];

    const int N = in_sizes[0] / F_IN;       // 50000
    const int E = in_sizes[7] / 2;          // 1600000
    const int G = N / SSUB;                 // 1000
    const int NH = N * HID;
    const int nblk = (N + 255) / 256;       // 196
    const int slice_size = (N + 7) / 8;     // 6250

    const int* src = edge;
    const int* dst = edge + E;

    // workspace layout
    char* ws = (char*)d_ws;
    float* dinv    = (float*)ws;                 ws += (size_t)N * 4;
    int*   cnt     = (int*)ws;                   ws += (size_t)N * 4;
    int*   row_ptr = (int*)ws;                   ws += (size_t)(N + 64) * 4;
    int*   cursor  = (int*)ws;                   ws += (size_t)N * 4;
    int*   blk_sum = (int*)ws;                   ws += (size_t)(nblk + 64) * 4;
    int*   blk_off = (int*)ws;                   ws += (size_t)(nblk + 64) * 4;
    int*   csr_src = (int*)ws;                   ws += (size_t)E * 4;
    unsigned short* hs0 = (unsigned short*)ws;   ws += (size_t)NH * 2;   // bf16 gather buf L1
    unsigned short* hs1 = (unsigned short*)ws;   ws += (size_t)NH * 2;   // bf16 gather buf L2
    float* h       = (float*)ws;                 ws += (size_t)NH * 4;   // fp32 relu'd hidden
    short* Bf1     = (short*)ws;                 ws += (size_t)2 * F_IN * HID * 2;  // hi+lo bf16
    short* Bf2     = (short*)ws;                 ws += (size_t)2 * HID * HID * 2;
    short* Bfl     = (short*)ws;                 ws += (size_t)2 * KFIN * HID * 2;

    float* out_final = (float*)d_out;                 // G*H
    float* emb       = out_final + (size_t)G * HID;   // N*H

    // ---- CSR build (also computes dinv) ----
    hipMemsetAsync(cnt, 0, (size_t)N * 4, stream);
    k_hist<<<(E + 255) / 256, 256, 0, stream>>>(dst, cnt, E);
    k_scan_local<<<nblk, 256, 0, stream>>>(cnt, row_ptr, dinv, blk_sum, N);
    k_scan_blk<<<1, 256, 0, stream>>>(blk_sum, blk_off, nblk);
    k_scan_add<<<nblk, 256, 0, stream>>>(row_ptr, cursor, blk_off, N, nblk);
    {
        int chunks = (E + 255) / 256;
        k_fill_csr<<<chunks * 8, 256, 0, stream>>>(src, dst, cursor, csr_src, E, slice_size);
    }

    // ---- weight splits ----
    k_wsplit<F_IN><<<(F_IN * HID + 255) / 256, 256, 0, stream>>>(W1, Bf1);
    k_wsplit<HID ><<<(HID  * HID + 255) / 256, 256, 0, stream>>>(W2, Bf2);
    k_wsplit<KFIN><<<(KFIN * HID + 255) / 256, 256, 0, stream>>>(Wl, Bfl);

    // ---- layer 1 ----
    k_gemm_mfma<F_IN><<<(N + 31) / 32, 128, 0, stream>>>(x, Bf1, dinv, hs0, N);
    k_agg<<<N, 128, 0, stream>>>(hs0, row_ptr, csr_src, dinv, b1, h, 1);

    // ---- layer 2 ----
    k_gemm_mfma<HID><<<(N + 31) / 32, 128, 0, stream>>>(h, Bf2, dinv, hs1, N);
    k_agg<<<N, 128, 0, stream>>>(hs1, row_ptr, csr_src, dinv, b2, emb, 0);

    // ---- final linear (bias init + MFMA split-K accumulate) ----
    k_final_init<<<(G * HID + 255) / 256, 256, 0, stream>>>(bl, out_final, G * HID);
    {
        dim3 grid((G + 31) / 32, 8);   // 8 K-slices of 800
        k_final_mfma<800, 160><<<grid, 128, 0, stream>>>(emb, Bfl, out_final, G);
    }
}